// Round 1
// baseline (147.085 us; speedup 1.0000x reference)
//
#include <hip/hip_runtime.h>
#include <hip/hip_bf16.h>

#define Bb 8
#define Tt 32
#define Ss 256
#define Dd 1024

typedef short short8 __attribute__((ext_vector_type(8)));
typedef float floatx4 __attribute__((ext_vector_type(4)));

__device__ __forceinline__ float tanh_fast(float x) {
    x = fminf(12.f, fmaxf(-12.f, x));
    float e = __expf(2.f * x);
    return 1.f - 2.f * __builtin_amdgcn_rcpf(e + 1.f);
}

__device__ __forceinline__ float dot4(float4 a, float4 b) {
    return a.x * b.x + a.y * b.y + a.z * b.z + a.w * b.w;
}

// s1 = (cumsum(src,T)/denom)*mask, cast to bf16.  16384 threads: idx>>13 picks source.
__global__ __launch_bounds__(256) void prefix_kernel(
        const float* __restrict__ src1, const float* __restrict__ src2,
        const float* __restrict__ m1, const float* __restrict__ m2,
        __hip_bfloat16* __restrict__ s1b, __hip_bfloat16* __restrict__ s2b) {
    int idx = blockIdx.x * 256 + threadIdx.x;
    int srcsel = idx >> 13;
    int bd = idx & 8191;
    int b = bd >> 10, d = bd & 1023;
    const float* sp = srcsel ? src2 : src1;
    const float* mp = srcsel ? m2 : m1;
    __hip_bfloat16* op = srcsel ? s2b : s1b;
    float a = 0.f;
    for (int t = 0; t < Tt; t++) {
        a += sp[(size_t)(b * Tt + t) * Dd + d];
        float inv = __builtin_amdgcn_rcpf((float)(t + 1));
        op[(size_t)(b * Tt + t) * Dd + d] = __float2bfloat16(a * inv * mp[b * Tt + t]);
    }
}

// cast W_q1, W_q2 to bf16 (1M elems each)
__global__ __launch_bounds__(256) void castw_kernel(
        const float* __restrict__ W1, const float* __restrict__ W2,
        __hip_bfloat16* __restrict__ W1b, __hip_bfloat16* __restrict__ W2b) {
    int i = blockIdx.x * 256 + threadIdx.x;   // grid = 4096 -> exactly 1M
    W1b[i] = __float2bfloat16(W1[i]);
    W2b[i] = __float2bfloat16(W2[i]);
}

// w_colsum partials: grid 64 = (4 d-blocks) x (16 j-chunks of 64)
__global__ __launch_bounds__(256) void wsum_part_kernel(
        const float* __restrict__ Wv, float* __restrict__ part) {
    int db = blockIdx.x & 3;
    int jc = blockIdx.x >> 2;
    int d = db * 256 + threadIdx.x;
    float a = 0.f;
    int j0 = jc * 64;
    for (int j = 0; j < 64; j++)
        a += Wv[(size_t)(j0 + j) * Dd + d];
    part[jc * Dd + d] = a;
}

__global__ __launch_bounds__(256) void wsum_final_kernel(
        const float* __restrict__ part, float* __restrict__ wsum) {
    int d = blockIdx.x * 256 + threadIdx.x;
    float a = 0.f;
    #pragma unroll
    for (int jc = 0; jc < 16; jc++)
        a += part[jc * Dd + d];
    wsum[d] = a;
}

// q[m, n] = sum_k s1[m,k]*W1[n,k] + s2[m,k]*W2[n,k] + bq1[n] + bq2[n]
// One wave per 16x16 C-tile; 1024 tiles = 256 blocks x 4 waves. bf16 MFMA 16x16x32.
// A-frag: A[m=lane&15][k=(lane>>4)*8+j]; B-frag: B[k=(lane>>4)*8+j][n=lane&15];
// C/D: col=lane&15, row=(lane>>4)*4+reg   (guide-verified layouts, m89/m120)
__global__ __launch_bounds__(256) void gemm_kernel(
        const __hip_bfloat16* __restrict__ s1b, const __hip_bfloat16* __restrict__ s2b,
        const __hip_bfloat16* __restrict__ W1b, const __hip_bfloat16* __restrict__ W2b,
        const float* __restrict__ bq1, const float* __restrict__ bq2,
        float* __restrict__ q) {
    const int wave = threadIdx.x >> 6;
    const int lane = threadIdx.x & 63;
    const int tile = blockIdx.x * 4 + wave;     // 0..1023
    const int m0 = (tile & 15) * 16;            // M = 256
    const int n0 = (tile >> 4) * 16;            // N = 1024
    const int lm = lane & 15;
    const int quad = lane >> 4;

    floatx4 acc1 = {0.f, 0.f, 0.f, 0.f};
    floatx4 acc2 = {0.f, 0.f, 0.f, 0.f};
    const __hip_bfloat16* arow1 = s1b + (size_t)(m0 + lm) * Dd;
    const __hip_bfloat16* arow2 = s2b + (size_t)(m0 + lm) * Dd;
    const __hip_bfloat16* brow1 = W1b + (size_t)(n0 + lm) * Dd;
    const __hip_bfloat16* brow2 = W2b + (size_t)(n0 + lm) * Dd;

    for (int k0 = 0; k0 < Dd; k0 += 32) {
        const int off = k0 + quad * 8;
        short8 a1 = *(const short8*)(arow1 + off);
        short8 b1 = *(const short8*)(brow1 + off);
        acc1 = __builtin_amdgcn_mfma_f32_16x16x32_bf16(a1, b1, acc1, 0, 0, 0);
        short8 a2 = *(const short8*)(arow2 + off);
        short8 b2 = *(const short8*)(brow2 + off);
        acc2 = __builtin_amdgcn_mfma_f32_16x16x32_bf16(a2, b2, acc2, 0, 0, 0);
    }

    const int n = n0 + lm;
    const float bias = bq1[n] + bq2[n];
    #pragma unroll
    for (int r = 0; r < 4; r++) {
        const int m = m0 + quad * 4 + r;
        q[(size_t)m * Dd + n] = acc1[r] + acc2[r] + bias;
    }
}

// One wave per (b,s). Lane holds mem/wsum for 16 d's (4 x float4 at d = j*256+lane*4).
// Per t: 16 tanh + dot, 64-lane butterfly reduce, lane0 writes the 2 outputs.
__global__ __launch_bounds__(256) void out_kernel(
        const float* __restrict__ q, const float* __restrict__ mem,
        const float* __restrict__ wsum, const float* __restrict__ Wc,
        const float* __restrict__ bc, float* __restrict__ out) {
    const int wave = threadIdx.x >> 6;
    const int lane = threadIdx.x & 63;
    const int gid = blockIdx.x * 4 + wave;      // b*S + s, 0..2047
    const int b = gid >> 8;
    const int s = gid & 255;
    const float* mrow = mem + (size_t)gid * Dd;

    float4 mv[4], wv[4];
    float pa0 = 0.f, pa1 = 0.f, pb0 = 0.f, pb1 = 0.f;
    #pragma unroll
    for (int j = 0; j < 4; j++) {
        const int d0 = j * 256 + lane * 4;
        mv[j] = *(const float4*)(mrow + d0);
        wv[j] = *(const float4*)(wsum + d0);
        float4 wa0 = *(const float4*)(Wc + d0);
        float4 wa1 = *(const float4*)(Wc + 2048 + d0);
        float4 wb0 = *(const float4*)(Wc + 1024 + d0);
        float4 wb1 = *(const float4*)(Wc + 2048 + 1024 + d0);
        pa0 += dot4(mv[j], wa0);
        pa1 += dot4(mv[j], wa1);
        pb0 += dot4(mv[j], wb0);
        pb1 += dot4(mv[j], wb1);
    }
    #pragma unroll
    for (int o = 32; o > 0; o >>= 1) {
        pa0 += __shfl_xor(pa0, o);
        pa1 += __shfl_xor(pa1, o);
        pb0 += __shfl_xor(pb0, o);
        pb1 += __shfl_xor(pb1, o);
    }
    const float bc0 = bc[0], bc1 = bc[1];

    for (int t = 0; t < Tt; t++) {
        const float* qrow = q + (size_t)(b * Tt + t) * Dd;
        float p = 0.f;
        #pragma unroll
        for (int j = 0; j < 4; j++) {
            const int d0 = j * 256 + lane * 4;
            float4 qv = *(const float4*)(qrow + d0);
            p = fmaf(tanh_fast(qv.x + mv[j].x), wv[j].x, p);
            p = fmaf(tanh_fast(qv.y + mv[j].y), wv[j].y, p);
            p = fmaf(tanh_fast(qv.z + mv[j].z), wv[j].z, p);
            p = fmaf(tanh_fast(qv.w + mv[j].w), wv[j].w, p);
        }
        #pragma unroll
        for (int o = 32; o > 0; o >>= 1) p += __shfl_xor(p, o);
        if (lane == 0) {
            const size_t o2 = ((size_t)(b * Tt + t) * Ss + s) * 2;
            out[o2]     = pa0 + p * pb0 + bc0;
            out[o2 + 1] = pa1 + p * pb1 + bc1;
        }
    }
}

extern "C" void kernel_launch(void* const* d_in, const int* in_sizes, int n_in,
                              void* d_out, int out_size, void* d_ws, size_t ws_size,
                              hipStream_t stream) {
    const float* src1 = (const float*)d_in[0];
    const float* src2 = (const float*)d_in[1];
    const float* mem  = (const float*)d_in[2];
    const float* m1   = (const float*)d_in[3];
    const float* m2   = (const float*)d_in[4];
    const float* Wq1  = (const float*)d_in[5];
    const float* bq1  = (const float*)d_in[6];
    const float* Wq2  = (const float*)d_in[7];
    const float* bq2  = (const float*)d_in[8];
    const float* Wc   = (const float*)d_in[9];
    const float* bc   = (const float*)d_in[10];
    const float* Wv   = (const float*)d_in[11];
    float* out = (float*)d_out;

    char* ws = (char*)d_ws;
    __hip_bfloat16* s1b = (__hip_bfloat16*)(ws);                         // 512 KB
    __hip_bfloat16* s2b = (__hip_bfloat16*)(ws + (512u << 10));          // 512 KB
    __hip_bfloat16* W1b = (__hip_bfloat16*)(ws + (1u << 20));            // 2 MB
    __hip_bfloat16* W2b = (__hip_bfloat16*)(ws + (3u << 20));            // 2 MB
    float* q    = (float*)(ws + (5u << 20));                             // 1 MB
    float* wsum = (float*)(ws + (6u << 20));                             // 4 KB
    float* part = (float*)(ws + (6u << 20) + 4096);                      // 64 KB

    prefix_kernel<<<64, 256, 0, stream>>>(src1, src2, m1, m2, s1b, s2b);
    castw_kernel<<<4096, 256, 0, stream>>>(Wq1, Wq2, W1b, W2b);
    wsum_part_kernel<<<64, 256, 0, stream>>>(Wv, part);
    wsum_final_kernel<<<4, 256, 0, stream>>>(part, wsum);
    gemm_kernel<<<256, 256, 0, stream>>>(s1b, s2b, W1b, W2b, bq1, bq2, q);
    out_kernel<<<512, 256, 0, stream>>>(q, mem, wsum, Wc, bc, out);
}

// Round 2
// 128.678 us; speedup vs baseline: 1.1430x; 1.1430x over previous
//
#include <hip/hip_runtime.h>
#include <hip/hip_bf16.h>

#define Bb 8
#define Tt 32
#define Ss 256
#define Dd 1024
// 2/ln(2): tanh(z) = 1 - 2*rcp(exp2(z*SCALE)+1)
#define SCALE 2.885390081777927f

typedef short short8 __attribute__((ext_vector_type(8)));
typedef float floatx4 __attribute__((ext_vector_type(4)));

__device__ __forceinline__ unsigned short bf16b(float x) {
    __hip_bfloat16 h = __float2bfloat16(x);
    return *(unsigned short*)&h;
}

__device__ __forceinline__ float dot4(float4 a, float4 b) {
    return a.x * b.x + a.y * b.y + a.z * b.z + a.w * b.w;
}

__device__ __forceinline__ float sigm_term(float q, float m, float w, float acc) {
    // acc += w * rcp(exp2(q+m)+1)   (q,m pre-scaled by 2/ln2)
    float e = __builtin_amdgcn_exp2f(q + m);
    return fmaf(w, __builtin_amdgcn_rcpf(e + 1.f), acc);
}

// Fused prep: blocks [0,1024): cast W_q1/W_q2 to bf16 (float4-vectorized);
// blocks [1024,1088): w_colsum partials; blocks [1088,1152): prefix-mean -> bf16.
__global__ __launch_bounds__(256) void prep_kernel(
        const float* __restrict__ src1, const float* __restrict__ src2,
        const float* __restrict__ m1, const float* __restrict__ m2,
        const float* __restrict__ W1, const float* __restrict__ W2,
        const float* __restrict__ Wv,
        unsigned short* __restrict__ W1b, unsigned short* __restrict__ W2b,
        unsigned short* __restrict__ s1b, unsigned short* __restrict__ s2b,
        float* __restrict__ part) {
    const int blk = blockIdx.x, tid = threadIdx.x;
    if (blk < 1024) {
        const int idx = blk * 256 + tid;            // 262144 float4 groups = 1M elems
        float4 a = ((const float4*)W1)[idx];
        float4 b = ((const float4*)W2)[idx];
        ushort4 oa = { bf16b(a.x), bf16b(a.y), bf16b(a.z), bf16b(a.w) };
        ushort4 ob = { bf16b(b.x), bf16b(b.y), bf16b(b.z), bf16b(b.w) };
        ((ushort4*)W1b)[idx] = oa;
        ((ushort4*)W2b)[idx] = ob;
    } else if (blk < 1088) {
        const int bb = blk - 1024;
        const int db = bb & 3, jc = bb >> 2;
        const int d = db * 256 + tid;
        float a = 0.f;
        const int j0 = jc * 64;
        for (int j = 0; j < 64; j++)
            a += Wv[(size_t)(j0 + j) * Dd + d];
        part[jc * Dd + d] = a;
    } else {
        const int idx = (blk - 1088) * 256 + tid;   // 16384 chains
        const int srcsel = idx >> 13;
        const int bd = idx & 8191;
        const int b = bd >> 10, d = bd & 1023;
        const float* sp = srcsel ? src2 : src1;
        const float* mp = srcsel ? m2 : m1;
        unsigned short* op = srcsel ? s2b : s1b;
        float a = 0.f;
        for (int t = 0; t < Tt; t++) {
            a += sp[(size_t)(b * Tt + t) * Dd + d];
            float inv = __builtin_amdgcn_rcpf((float)(t + 1));
            op[(size_t)(b * Tt + t) * Dd + d] = bf16b(a * inv * mp[b * Tt + t]);
        }
    }
}

// blocks [0,512): one wave computes 16x32 of q' = SCALE*(s1@W1^T + s2@W2^T + b1 + b2)
//   (A-frag reused across both n-tiles; both source GEMMs chain into one acc)
// blocks [512,528): wsum final reduce (1024 d / 64 lanes)
__global__ __launch_bounds__(64) void gemm_kernel(
        const unsigned short* __restrict__ s1b, const unsigned short* __restrict__ s2b,
        const unsigned short* __restrict__ W1b, const unsigned short* __restrict__ W2b,
        const float* __restrict__ bq1, const float* __restrict__ bq2,
        const float* __restrict__ part,
        float* __restrict__ qp, float* __restrict__ wsum) {
    const int blk = blockIdx.x;
    const int lane = threadIdx.x;
    if (blk >= 512) {
        const int d = (blk - 512) * 64 + lane;
        float a = 0.f;
        #pragma unroll
        for (int jc = 0; jc < 16; jc++)
            a += part[jc * Dd + d];
        wsum[d] = a;
        return;
    }
    const int m0 = (blk & 15) * 16;       // M = 256
    const int n0 = (blk >> 4) * 32;       // N = 1024, two 16-wide n-tiles
    const int lm = lane & 15;
    const int quad = lane >> 4;

    floatx4 acc0 = {0.f, 0.f, 0.f, 0.f};
    floatx4 acc1 = {0.f, 0.f, 0.f, 0.f};
    const unsigned short* a1p = s1b + (size_t)(m0 + lm) * Dd;
    const unsigned short* a2p = s2b + (size_t)(m0 + lm) * Dd;
    const unsigned short* b1a = W1b + (size_t)(n0 + lm) * Dd;
    const unsigned short* b1b = W1b + (size_t)(n0 + 16 + lm) * Dd;
    const unsigned short* b2a = W2b + (size_t)(n0 + lm) * Dd;
    const unsigned short* b2b = W2b + (size_t)(n0 + 16 + lm) * Dd;

    #pragma unroll 2
    for (int k0 = 0; k0 < Dd; k0 += 32) {
        const int off = k0 + quad * 8;
        short8 a1 = *(const short8*)(a1p + off);
        short8 a2 = *(const short8*)(a2p + off);
        short8 vb1a = *(const short8*)(b1a + off);
        short8 vb2a = *(const short8*)(b2a + off);
        short8 vb1b = *(const short8*)(b1b + off);
        short8 vb2b = *(const short8*)(b2b + off);
        acc0 = __builtin_amdgcn_mfma_f32_16x16x32_bf16(a1, vb1a, acc0, 0, 0, 0);
        acc1 = __builtin_amdgcn_mfma_f32_16x16x32_bf16(a1, vb1b, acc1, 0, 0, 0);
        acc0 = __builtin_amdgcn_mfma_f32_16x16x32_bf16(a2, vb2a, acc0, 0, 0, 0);
        acc1 = __builtin_amdgcn_mfma_f32_16x16x32_bf16(a2, vb2b, acc1, 0, 0, 0);
    }

    const int na = n0 + lm, nb = n0 + 16 + lm;
    const float biasa = bq1[na] + bq2[na];
    const float biasb = bq1[nb] + bq2[nb];
    #pragma unroll
    for (int r = 0; r < 4; r++) {
        const int m = m0 + quad * 4 + r;   // C/D: col=lane&15, row=quad*4+reg
        qp[(size_t)m * Dd + na] = SCALE * (acc0[r] + biasa);
        qp[(size_t)m * Dd + nb] = SCALE * (acc1[r] + biasb);
    }
}

// One wave per (b, s, t-half). 4096 waves = 1024 blocks x 4 waves (4 waves/SIMD).
// Inner: p = sum_d w[d]*rcp(exp2(q'[d]+m'[d])+1);  out = C - D*p.
__global__ __launch_bounds__(256) void out_kernel(
        const float* __restrict__ qp, const float* __restrict__ mem,
        const float* __restrict__ wsum, const float* __restrict__ Wc,
        const float* __restrict__ bc, float* __restrict__ out) {
    const int wave = threadIdx.x >> 6;
    const int lane = threadIdx.x & 63;
    const int gid = blockIdx.x * 4 + wave;   // 0..4095
    const int half = gid >> 11;
    const int bs = gid & 2047;
    const int b = bs >> 8, s = bs & 255;
    const float* mrow = mem + (size_t)bs * Dd;

    float4 mv[4], wv[4];
    float pa0 = 0.f, pa1 = 0.f, pb0 = 0.f, pb1 = 0.f, Wl = 0.f;
    #pragma unroll
    for (int j = 0; j < 4; j++) {
        const int d0 = j * 256 + lane * 4;
        float4 m_ = *(const float4*)(mrow + d0);
        wv[j] = *(const float4*)(wsum + d0);
        Wl += wv[j].x + wv[j].y + wv[j].z + wv[j].w;
        float4 wa0 = *(const float4*)(Wc + d0);
        float4 wa1 = *(const float4*)(Wc + 2048 + d0);
        float4 wb0 = *(const float4*)(Wc + 1024 + d0);
        float4 wb1 = *(const float4*)(Wc + 3072 + d0);
        pa0 += dot4(m_, wa0);
        pa1 += dot4(m_, wa1);
        pb0 += dot4(m_, wb0);
        pb1 += dot4(m_, wb1);
        mv[j].x = m_.x * SCALE; mv[j].y = m_.y * SCALE;
        mv[j].z = m_.z * SCALE; mv[j].w = m_.w * SCALE;
    }
    #pragma unroll
    for (int o = 32; o > 0; o >>= 1) {
        pa0 += __shfl_xor(pa0, o);
        pa1 += __shfl_xor(pa1, o);
        pb0 += __shfl_xor(pb0, o);
        pb1 += __shfl_xor(pb1, o);
        Wl  += __shfl_xor(Wl, o);
    }
    const float C0 = pa0 + Wl * pb0 + bc[0];
    const float C1 = pa1 + Wl * pb1 + bc[1];
    const float D0 = 2.f * pb0, D1 = 2.f * pb1;

    const int t0 = half * 16;
    for (int tp = 0; tp < 16; tp += 2) {
        const float* q0 = qp + (size_t)(b * Tt + t0 + tp) * Dd;
        const float* q1 = q0 + Dd;
        float p0 = 0.f, p1 = 0.f;
        #pragma unroll
        for (int j = 0; j < 4; j++) {
            const int d0 = j * 256 + lane * 4;
            float4 x0 = *(const float4*)(q0 + d0);
            float4 x1 = *(const float4*)(q1 + d0);
            p0 = sigm_term(x0.x, mv[j].x, wv[j].x, p0);
            p0 = sigm_term(x0.y, mv[j].y, wv[j].y, p0);
            p0 = sigm_term(x0.z, mv[j].z, wv[j].z, p0);
            p0 = sigm_term(x0.w, mv[j].w, wv[j].w, p0);
            p1 = sigm_term(x1.x, mv[j].x, wv[j].x, p1);
            p1 = sigm_term(x1.y, mv[j].y, wv[j].y, p1);
            p1 = sigm_term(x1.z, mv[j].z, wv[j].z, p1);
            p1 = sigm_term(x1.w, mv[j].w, wv[j].w, p1);
        }
        #pragma unroll
        for (int o = 32; o > 0; o >>= 1) {
            p0 += __shfl_xor(p0, o);
            p1 += __shfl_xor(p1, o);
        }
        if (lane == 0) {
            const int tA = t0 + tp;
            float2 oA = { C0 - D0 * p0, C1 - D1 * p0 };
            float2 oB = { C0 - D0 * p1, C1 - D1 * p1 };
            *(float2*)(out + ((size_t)(b * Tt + tA) * Ss + s) * 2) = oA;
            *(float2*)(out + ((size_t)(b * Tt + tA + 1) * Ss + s) * 2) = oB;
        }
    }
}

extern "C" void kernel_launch(void* const* d_in, const int* in_sizes, int n_in,
                              void* d_out, int out_size, void* d_ws, size_t ws_size,
                              hipStream_t stream) {
    const float* src1 = (const float*)d_in[0];
    const float* src2 = (const float*)d_in[1];
    const float* mem  = (const float*)d_in[2];
    const float* m1   = (const float*)d_in[3];
    const float* m2   = (const float*)d_in[4];
    const float* Wq1  = (const float*)d_in[5];
    const float* bq1  = (const float*)d_in[6];
    const float* Wq2  = (const float*)d_in[7];
    const float* bq2  = (const float*)d_in[8];
    const float* Wc   = (const float*)d_in[9];
    const float* bc   = (const float*)d_in[10];
    const float* Wv   = (const float*)d_in[11];
    float* out = (float*)d_out;

    char* ws = (char*)d_ws;
    unsigned short* s1b = (unsigned short*)(ws);                 // 512 KB
    unsigned short* s2b = (unsigned short*)(ws + (512u << 10));  // 512 KB
    unsigned short* W1b = (unsigned short*)(ws + (1u << 20));    // 2 MB
    unsigned short* W2b = (unsigned short*)(ws + (3u << 20));    // 2 MB
    float* qp   = (float*)(ws + (5u << 20));                     // 1 MB (pre-scaled q)
    float* wsum = (float*)(ws + (6u << 20));                     // 4 KB
    float* part = (float*)(ws + (6u << 20) + 4096);              // 64 KB

    prep_kernel<<<1152, 256, 0, stream>>>(src1, src2, m1, m2, Wq1, Wq2, Wv,
                                          W1b, W2b, s1b, s2b, part);
    gemm_kernel<<<528, 64, 0, stream>>>(s1b, s2b, W1b, W2b, bq1, bq2, part, qp, wsum);
    out_kernel<<<1024, 256, 0, stream>>>(qp, mem, wsum, Wc, bc, out);
}

// Round 3
// 126.025 us; speedup vs baseline: 1.1671x; 1.0211x over previous
//
#include <hip/hip_runtime.h>
#include <hip/hip_bf16.h>

#define Bb 8
#define Tt 32
#define Ss 256
#define Dd 1024
// 2/ln(2): tanh(z) = 1 - 2*rcp(exp2(z*SCALE)+1)
#define SCALE 2.885390081777927f

typedef short short8 __attribute__((ext_vector_type(8)));
typedef float floatx4 __attribute__((ext_vector_type(4)));

__device__ __forceinline__ unsigned short bf16b(float x) {
    __hip_bfloat16 h = __float2bfloat16(x);
    return *(unsigned short*)&h;
}

__device__ __forceinline__ float dot4(float4 a, float4 b) {
    return a.x * b.x + a.y * b.y + a.z * b.z + a.w * b.w;
}

__device__ __forceinline__ float sigm_term(float q, float m, float w, float acc) {
    // acc += w * rcp(exp2(q+m)+1)   (q,m pre-scaled by 2/ln2)
    float e = __builtin_amdgcn_exp2f(q + m);
    return fmaf(w, __builtin_amdgcn_rcpf(e + 1.f), acc);
}

// Fused prep: blocks [0,1024): cast W_q1/W_q2 to bf16 (float4-vectorized);
// blocks [1024,1088): w_colsum partials; blocks [1088,1152): prefix-mean -> bf16.
__global__ __launch_bounds__(256) void prep_kernel(
        const float* __restrict__ src1, const float* __restrict__ src2,
        const float* __restrict__ m1, const float* __restrict__ m2,
        const float* __restrict__ W1, const float* __restrict__ W2,
        const float* __restrict__ Wv,
        unsigned short* __restrict__ W1b, unsigned short* __restrict__ W2b,
        unsigned short* __restrict__ s1b, unsigned short* __restrict__ s2b,
        float* __restrict__ part) {
    const int blk = blockIdx.x, tid = threadIdx.x;
    if (blk < 1024) {
        const int idx = blk * 256 + tid;            // 262144 float4 groups = 1M elems
        float4 a = ((const float4*)W1)[idx];
        float4 b = ((const float4*)W2)[idx];
        ushort4 oa = { bf16b(a.x), bf16b(a.y), bf16b(a.z), bf16b(a.w) };
        ushort4 ob = { bf16b(b.x), bf16b(b.y), bf16b(b.z), bf16b(b.w) };
        ((ushort4*)W1b)[idx] = oa;
        ((ushort4*)W2b)[idx] = ob;
    } else if (blk < 1088) {
        const int bb = blk - 1024;
        const int db = bb & 3, jc = bb >> 2;
        const int d = db * 256 + tid;
        float a = 0.f;
        const int j0 = jc * 64;
        for (int j = 0; j < 64; j++)
            a += Wv[(size_t)(j0 + j) * Dd + d];
        part[jc * Dd + d] = a;
    } else {
        const int idx = (blk - 1088) * 256 + tid;   // 16384 chains
        const int srcsel = idx >> 13;
        const int bd = idx & 8191;
        const int b = bd >> 10, d = bd & 1023;
        const float* sp = srcsel ? src2 : src1;
        const float* mp = srcsel ? m2 : m1;
        unsigned short* op = srcsel ? s2b : s1b;
        float a = 0.f;
        for (int t = 0; t < Tt; t++) {
            a += sp[(size_t)(b * Tt + t) * Dd + d];
            float inv = __builtin_amdgcn_rcpf((float)(t + 1));
            op[(size_t)(b * Tt + t) * Dd + d] = bf16b(a * inv * mp[b * Tt + t]);
        }
    }
}

// blocks [0,512): one wave computes a 16x32 tile of
//      q' = SCALE*(s1@W1^T + s2@W2^T + b1 + b2)
// blocks [512,528): wsum final reduce (1024 d / 64 lanes)
// blocks [528,2576): pa/pb precompute — one wave per (b,s) row:
//      pab[bs] = { mem.wa0, mem.wa1, mem.wb0, mem.wb1 }
__global__ __launch_bounds__(64) void gemm_kernel(
        const unsigned short* __restrict__ s1b, const unsigned short* __restrict__ s2b,
        const unsigned short* __restrict__ W1b, const unsigned short* __restrict__ W2b,
        const float* __restrict__ bq1, const float* __restrict__ bq2,
        const float* __restrict__ part, const float* __restrict__ mem,
        const float* __restrict__ Wc,
        float* __restrict__ qp, float* __restrict__ wsum,
        float* __restrict__ pab) {
    const int blk = blockIdx.x;
    const int lane = threadIdx.x;
    if (blk >= 528) {                        // pa/pb rows
        const int bs = blk - 528;            // 0..2047
        const float4* mrow = (const float4*)mem + (size_t)bs * 256;
        const float4* Wc4 = (const float4*)Wc;
        float a0 = 0.f, a1 = 0.f, b0 = 0.f, b1 = 0.f;
        #pragma unroll
        for (int j = 0; j < 4; j++) {
            const int idx = j * 64 + lane;
            float4 m_ = mrow[idx];
            a0 += dot4(m_, Wc4[idx]);
            b0 += dot4(m_, Wc4[256 + idx]);
            a1 += dot4(m_, Wc4[512 + idx]);
            b1 += dot4(m_, Wc4[768 + idx]);
        }
        #pragma unroll
        for (int o = 32; o > 0; o >>= 1) {
            a0 += __shfl_xor(a0, o);
            a1 += __shfl_xor(a1, o);
            b0 += __shfl_xor(b0, o);
            b1 += __shfl_xor(b1, o);
        }
        if (lane == 0) {
            float4 r = { a0, a1, b0, b1 };
            ((float4*)pab)[bs] = r;
        }
        return;
    }
    if (blk >= 512) {                        // wsum final
        const int d = (blk - 512) * 64 + lane;
        float a = 0.f;
        #pragma unroll
        for (int jc = 0; jc < 16; jc++)
            a += part[jc * Dd + d];
        wsum[d] = a;
        return;
    }
    const int m0 = (blk & 15) * 16;       // M = 256
    const int n0 = (blk >> 4) * 32;       // N = 1024, two 16-wide n-tiles
    const int lm = lane & 15;
    const int quad = lane >> 4;

    floatx4 acc0 = {0.f, 0.f, 0.f, 0.f};
    floatx4 acc1 = {0.f, 0.f, 0.f, 0.f};
    const unsigned short* a1p = s1b + (size_t)(m0 + lm) * Dd;
    const unsigned short* a2p = s2b + (size_t)(m0 + lm) * Dd;
    const unsigned short* b1a = W1b + (size_t)(n0 + lm) * Dd;
    const unsigned short* b1b = W1b + (size_t)(n0 + 16 + lm) * Dd;
    const unsigned short* b2a = W2b + (size_t)(n0 + lm) * Dd;
    const unsigned short* b2b = W2b + (size_t)(n0 + 16 + lm) * Dd;

    #pragma unroll 2
    for (int k0 = 0; k0 < Dd; k0 += 32) {
        const int off = k0 + quad * 8;
        short8 a1 = *(const short8*)(a1p + off);
        short8 a2 = *(const short8*)(a2p + off);
        short8 vb1a = *(const short8*)(b1a + off);
        short8 vb2a = *(const short8*)(b2a + off);
        short8 vb1b = *(const short8*)(b1b + off);
        short8 vb2b = *(const short8*)(b2b + off);
        acc0 = __builtin_amdgcn_mfma_f32_16x16x32_bf16(a1, vb1a, acc0, 0, 0, 0);
        acc1 = __builtin_amdgcn_mfma_f32_16x16x32_bf16(a1, vb1b, acc1, 0, 0, 0);
        acc0 = __builtin_amdgcn_mfma_f32_16x16x32_bf16(a2, vb2a, acc0, 0, 0, 0);
        acc1 = __builtin_amdgcn_mfma_f32_16x16x32_bf16(a2, vb2b, acc1, 0, 0, 0);
    }

    const int na = n0 + lm, nb = n0 + 16 + lm;
    const float biasa = bq1[na] + bq2[na];
    const float biasb = bq1[nb] + bq2[nb];
    #pragma unroll
    for (int r = 0; r < 4; r++) {
        const int m = m0 + quad * 4 + r;   // C/D: col=lane&15, row=quad*4+reg
        qp[(size_t)m * Dd + na] = SCALE * (acc0[r] + biasa);
        qp[(size_t)m * Dd + nb] = SCALE * (acc1[r] + biasb);
    }
}

// One wave per (b, 4-t tile, 4-s tile): 8 b * 8 tq * 64 sq = 4096 waves.
// 16 independent sigmoid accumulator chains; q and mem each read once per
// 4-wide opposing tile -> 134 MB L2 total, under the trans-pipe floor.
__global__ __launch_bounds__(256) void out_kernel(
        const float* __restrict__ qp, const float* __restrict__ mem,
        const float* __restrict__ wsum, const float* __restrict__ pab,
        const float* __restrict__ bc, float* __restrict__ out) {
    const int wave = threadIdx.x >> 6;
    const int lane = threadIdx.x & 63;
    const int gid = blockIdx.x * 4 + wave;   // 0..4095
    const int b = gid >> 9;
    const int r = gid & 511;
    const int tq = r >> 6, sq = r & 63;
    const int t0 = tq * 4, s0 = sq * 4;
    const int bs0 = b * Ss + s0;

    const float4* mem4 = (const float4*)mem;
    const float4* q4 = (const float4*)qp;
    const float4* wsum4 = (const float4*)wsum;

    float4 wv[4];
    float Wl = 0.f;
    #pragma unroll
    for (int j = 0; j < 4; j++) {
        wv[j] = wsum4[j * 64 + lane];
        Wl += wv[j].x + wv[j].y + wv[j].z + wv[j].w;
    }
    #pragma unroll
    for (int o = 32; o > 0; o >>= 1) Wl += __shfl_xor(Wl, o);

    const float bc0 = bc[0], bc1 = bc[1];
    float C0[4], C1[4], D0[4], D1[4];
    #pragma unroll
    for (int si = 0; si < 4; si++) {
        float4 pv = ((const float4*)pab)[bs0 + si];   // {pa0,pa1,pb0,pb1}
        C0[si] = pv.x + Wl * pv.z + bc0;
        C1[si] = pv.y + Wl * pv.w + bc1;
        D0[si] = 2.f * pv.z;
        D1[si] = 2.f * pv.w;
    }

    float p[4][4];
    #pragma unroll
    for (int ti = 0; ti < 4; ti++)
        #pragma unroll
        for (int si = 0; si < 4; si++) p[ti][si] = 0.f;

    #pragma unroll
    for (int j = 0; j < 4; j++) {
        const int idx = j * 64 + lane;
        float4 mj[4], qj[4];
        #pragma unroll
        for (int si = 0; si < 4; si++) {
            float4 m_ = mem4[(size_t)(bs0 + si) * 256 + idx];
            mj[si].x = m_.x * SCALE; mj[si].y = m_.y * SCALE;
            mj[si].z = m_.z * SCALE; mj[si].w = m_.w * SCALE;
        }
        #pragma unroll
        for (int ti = 0; ti < 4; ti++)
            qj[ti] = q4[(size_t)(b * Tt + t0 + ti) * 256 + idx];
        const float4 w_ = wv[j];
        #pragma unroll
        for (int ti = 0; ti < 4; ti++) {
            #pragma unroll
            for (int si = 0; si < 4; si++) {
                float acc = p[ti][si];
                acc = sigm_term(qj[ti].x, mj[si].x, w_.x, acc);
                acc = sigm_term(qj[ti].y, mj[si].y, w_.y, acc);
                acc = sigm_term(qj[ti].z, mj[si].z, w_.z, acc);
                acc = sigm_term(qj[ti].w, mj[si].w, w_.w, acc);
                p[ti][si] = acc;
            }
        }
    }

    #pragma unroll
    for (int ti = 0; ti < 4; ti++)
        #pragma unroll
        for (int si = 0; si < 4; si++) {
            float v = p[ti][si];
            #pragma unroll
            for (int o = 32; o > 0; o >>= 1) v += __shfl_xor(v, o);
            p[ti][si] = v;
        }

    if (lane == 0) {
        #pragma unroll
        for (int ti = 0; ti < 4; ti++) {
            const size_t rowo = ((size_t)(b * Tt + t0 + ti) * Ss + s0) * 2;
            #pragma unroll
            for (int si = 0; si < 4; si++) {
                float2 o2 = { C0[si] - D0[si] * p[ti][si],
                              C1[si] - D1[si] * p[ti][si] };
                *(float2*)(out + rowo + si * 2) = o2;
            }
        }
    }
}

extern "C" void kernel_launch(void* const* d_in, const int* in_sizes, int n_in,
                              void* d_out, int out_size, void* d_ws, size_t ws_size,
                              hipStream_t stream) {
    const float* src1 = (const float*)d_in[0];
    const float* src2 = (const float*)d_in[1];
    const float* mem  = (const float*)d_in[2];
    const float* m1   = (const float*)d_in[3];
    const float* m2   = (const float*)d_in[4];
    const float* Wq1  = (const float*)d_in[5];
    const float* bq1  = (const float*)d_in[6];
    const float* Wq2  = (const float*)d_in[7];
    const float* bq2  = (const float*)d_in[8];
    const float* Wc   = (const float*)d_in[9];
    const float* bc   = (const float*)d_in[10];
    const float* Wv   = (const float*)d_in[11];
    float* out = (float*)d_out;

    char* ws = (char*)d_ws;
    unsigned short* s1b = (unsigned short*)(ws);                 // 512 KB
    unsigned short* s2b = (unsigned short*)(ws + (512u << 10));  // 512 KB
    unsigned short* W1b = (unsigned short*)(ws + (1u << 20));    // 2 MB
    unsigned short* W2b = (unsigned short*)(ws + (3u << 20));    // 2 MB
    float* qp   = (float*)(ws + (5u << 20));                     // 1 MB (pre-scaled q)
    float* wsum = (float*)(ws + (6u << 20));                     // 4 KB
    float* part = (float*)(ws + (6u << 20) + 4096);              // 64 KB
    float* pab  = (float*)(ws + (6u << 20) + 4096 + 65536);      // 32 KB

    prep_kernel<<<1152, 256, 0, stream>>>(src1, src2, m1, m2, Wq1, Wq2, Wv,
                                          W1b, W2b, s1b, s2b, part);
    gemm_kernel<<<2576, 64, 0, stream>>>(s1b, s2b, W1b, W2b, bq1, bq2, part,
                                         mem, Wc, qp, wsum, pab);
    out_kernel<<<1024, 256, 0, stream>>>(qp, mem, wsum, pab, bc, out);
}